// Round 6
// baseline (1096.152 us; speedup 1.0000x reference)
//
#include <hip/hip_runtime.h>
#include <stdint.h>

// BinHD: samples [8192,10000] f32 {0,1}, classes [1000,10000] f32 {0,1}
// out [8192,1000] f32 = Hamming = popcount(xor) over bit-packed rows (exact).
#define N_ROWS 8192
#define C_CLS  1000
#define D_DIM  10000
#define W64P   160            // u64 words per packed row, padded (157 used)
#define W32P   (W64P * 2)     // 320 u32 words per packed row
#define BSTR   132            // B LDS row stride (pads 128 -> kills conflicts)
#define CW     32             // chunk width in u32 words
#define NCHUNK 10             // 10 chunks x 32 words = 320

// ---------------------------------------------------------------------------
// Kernel 1: bit-pack via float4 + 4 wave ballots. One wave per row.
// ---------------------------------------------------------------------------
__global__ __launch_bounds__(256) void pack_kernel(
    const float* __restrict__ samples, const float* __restrict__ classes,
    unsigned long long* __restrict__ pA, unsigned long long* __restrict__ pB)
{
    int gwave = (blockIdx.x * 256 + threadIdx.x) >> 6;
    int lane  = threadIdx.x & 63;
    if (gwave >= N_ROWS + C_CLS) return;   // wave-uniform exit

    const float* src;
    unsigned long long* dst;
    if (gwave < N_ROWS) {
        src = samples + (size_t)gwave * D_DIM;
        dst = pA + (size_t)gwave * W64P;
    } else {
        int r = gwave - N_ROWS;
        src = classes + (size_t)r * D_DIM;
        dst = pB + (size_t)r * W64P;
    }

    #pragma unroll 4
    for (int it = 0; it < 39; ++it) {       // dims 0..9983 -> words 0..155
        float4 v = *(const float4*)(src + it * 256 + lane * 4);
        unsigned long long m0 = __ballot(v.x > 0.5f);
        unsigned long long m1 = __ballot(v.y > 0.5f);
        unsigned long long m2 = __ballot(v.z > 0.5f);
        unsigned long long m3 = __ballot(v.w > 0.5f);
        if (lane < 2) {
            ulonglong2 st;
            st.x = lane ? m2 : m0;
            st.y = lane ? m3 : m1;
            *(ulonglong2*)(dst + it * 4 + lane * 2) = st;
        }
    }
    {   // tail: dims 9984..9999 -> words 156..159 (zero-padded)
        float4 v = make_float4(0.f, 0.f, 0.f, 0.f);
        if (lane < 4) v = *(const float4*)(src + 9984 + lane * 4);
        unsigned long long m0 = __ballot(v.x > 0.5f);
        unsigned long long m1 = __ballot(v.y > 0.5f);
        unsigned long long m2 = __ballot(v.z > 0.5f);
        unsigned long long m3 = __ballot(v.w > 0.5f);
        if (lane < 2) {
            ulonglong2 st;
            st.x = lane ? m2 : m0;
            st.y = lane ? m3 : m1;
            *(ulonglong2*)(dst + 156 + lane * 2) = st;
        }
    }
}

// ---------------------------------------------------------------------------
// Kernel 2: Hamming GEMM. 128x128 tile, 512 threads, 4x8 acc/thread (32 regs).
// Low register pressure by design (~90 live) + __launch_bounds__(512,4)
// -> VGPR<=128 -> 4 waves/SIMD (16 waves/CU): 2x R1's latency hiding.
// R1's proven 2-barrier structure (load -> barrier -> LDS store -> barrier
// -> compute). CW=32 halves barrier count vs R1.
//   As [128][32w], 16B-granule XOR swizzle keyed (row>>2)&3 (conflict-free
//     reads for the 4-rows-per-thread geometry; per-phase-clean writes).
//   Bs transposed [32 kw][BSTR cols], 2-way reads (free).
// ---------------------------------------------------------------------------
__global__ __launch_bounds__(512, 4) void hd_kernel(
    const uint32_t* __restrict__ pA, const uint32_t* __restrict__ pB,
    float* __restrict__ out)
{
    __shared__ __attribute__((aligned(16))) uint32_t As[128 * CW];
    __shared__ __attribute__((aligned(16))) uint32_t Bs[CW * BSTR];

    const int tid  = threadIdx.x;
    const int row0 = blockIdx.x * 128;
    const int col0 = blockIdx.y * 128;

    const int rg   = tid >> 4;               // 0..31 row group (4 rows each)
    const int cg   = tid & 15;               // 0..15 col group (8 cols each)
    const int trow = rg * 4;
    const int tcol = (cg & 7) * 4 + (cg >> 3) * 64;  // cols tcol..+3, +32..+35
    const int ka   = rg & 3;                 // A read swizzle key = (row>>2)&3

    // staging: granule u = tid + 512*i (i=0,1); rr = u>>3, gg = u&7
    const int rr0 = tid >> 3,          gg0 = tid & 7;
    const int rr1 = (tid + 512) >> 3,  gg1 = tid & 7;
    const uint32_t* gA0 = pA + (size_t)(row0 + rr0) * W32P + gg0 * 4;
    const uint32_t* gA1 = pA + (size_t)(row0 + rr1) * W32P + gg1 * 4;
    const bool okB0 = (col0 + rr0) < C_CLS;
    const bool okB1 = (col0 + rr1) < C_CLS;
    const uint32_t* gB0 = pB + (size_t)(okB0 ? (col0 + rr0) : 0) * W32P + gg0 * 4;
    const uint32_t* gB1 = pB + (size_t)(okB1 ? (col0 + rr1) : 0) * W32P + gg1 * 4;

    uint32_t acc[4][8];
    #pragma unroll
    for (int r = 0; r < 4; ++r)
        #pragma unroll
        for (int c = 0; c < 8; ++c) acc[r][c] = 0;

    for (int ch = 0; ch < NCHUNK; ++ch) {
        // ---- global loads for this chunk (16 staging regs only) ----
        const int off = ch * CW;
        uint4 av0 = *(const uint4*)(gA0 + off);
        uint4 av1 = *(const uint4*)(gA1 + off);
        uint4 bv0 = okB0 ? *(const uint4*)(gB0 + off) : make_uint4(0u,0u,0u,0u);
        uint4 bv1 = okB1 ? *(const uint4*)(gB1 + off) : make_uint4(0u,0u,0u,0u);

        __syncthreads();   // previous chunk's LDS reads complete

        *(uint4*)&As[rr0 * CW + ((gg0 ^ ((rr0 >> 2) & 3)) << 2)] = av0;
        *(uint4*)&As[rr1 * CW + ((gg1 ^ ((rr1 >> 2) & 3)) << 2)] = av1;
        Bs[(gg0 * 4 + 0) * BSTR + rr0] = bv0.x;
        Bs[(gg0 * 4 + 1) * BSTR + rr0] = bv0.y;
        Bs[(gg0 * 4 + 2) * BSTR + rr0] = bv0.z;
        Bs[(gg0 * 4 + 3) * BSTR + rr0] = bv0.w;
        Bs[(gg1 * 4 + 0) * BSTR + rr1] = bv1.x;
        Bs[(gg1 * 4 + 1) * BSTR + rr1] = bv1.y;
        Bs[(gg1 * 4 + 2) * BSTR + rr1] = bv1.z;
        Bs[(gg1 * 4 + 3) * BSTR + rr1] = bv1.w;

        __syncthreads();   // LDS tile ready

        #pragma unroll
        for (int g = 0; g < 8; ++g) {
            // 8 B uint4s for this K-granule (32 regs, the pressure peak)
            uint4 b0[4], b1[4];
            #pragma unroll
            for (int j = 0; j < 4; ++j) {
                b0[j] = *(const uint4*)&Bs[(g * 4 + j) * BSTR + tcol];
                b1[j] = *(const uint4*)&Bs[(g * 4 + j) * BSTR + tcol + 32];
            }
            #pragma unroll
            for (int r = 0; r < 4; ++r) {
                uint4 a = *(const uint4*)&As[(trow + r) * CW + ((g ^ ka) << 2)];
                #pragma unroll
                for (int j = 0; j < 4; ++j) {
                    uint32_t aw = (j == 0) ? a.x : (j == 1) ? a.y
                                : (j == 2) ? a.z : a.w;
                    acc[r][0] += __popc(aw ^ b0[j].x);
                    acc[r][1] += __popc(aw ^ b0[j].y);
                    acc[r][2] += __popc(aw ^ b0[j].z);
                    acc[r][3] += __popc(aw ^ b0[j].w);
                    acc[r][4] += __popc(aw ^ b1[j].x);
                    acc[r][5] += __popc(aw ^ b1[j].y);
                    acc[r][6] += __popc(aw ^ b1[j].z);
                    acc[r][7] += __popc(aw ^ b1[j].w);
                }
            }
        }
    }

    // ---- epilogue: dense float4 stores (lane-contiguous 128B lines) ----
    #pragma unroll
    for (int r = 0; r < 4; ++r) {
        int grow = row0 + trow + r;
        #pragma unroll
        for (int c4 = 0; c4 < 2; ++c4) {
            int gcol = col0 + tcol + c4 * 32;
            if (gcol < C_CLS) {
                float4 v = make_float4((float)acc[r][c4 * 4 + 0],
                                       (float)acc[r][c4 * 4 + 1],
                                       (float)acc[r][c4 * 4 + 2],
                                       (float)acc[r][c4 * 4 + 3]);
                *(float4*)(out + (size_t)grow * C_CLS + gcol) = v;
            }
        }
    }
}

extern "C" void kernel_launch(void* const* d_in, const int* in_sizes, int n_in,
                              void* d_out, int out_size, void* d_ws, size_t ws_size,
                              hipStream_t stream) {
    const float* samples = (const float*)d_in[0];   // [8192, 10000] f32
    const float* classes = (const float*)d_in[1];   // [1000, 10000] f32
    float* out = (float*)d_out;                     // [8192, 1000] f32

    unsigned long long* pA = (unsigned long long*)d_ws;          // 10.49 MB
    unsigned long long* pB = pA + (size_t)N_ROWS * W64P;         // +1.28 MB

    int waves  = N_ROWS + C_CLS;
    int blocks = (waves + 3) / 4;
    pack_kernel<<<blocks, 256, 0, stream>>>(samples, classes, pA, pB);

    dim3 grid(N_ROWS / 128, 8);              // 64 x 8 = 512 blocks (2/CU)
    hd_kernel<<<grid, 512, 0, stream>>>((const uint32_t*)pA, (const uint32_t*)pB, out);
}